// Round 6
// baseline (44.590 us; speedup 1.0000x reference)
//
#include <hip/hip_runtime.h>
#include <math.h>

#define SEQ 30
#define H 64
#define VOCAB 128000

#define NB 1000
#define ITERS 8               // rows per block = 16 * ITERS = 128
#define ROWS_PER_BLOCK 128

// ws layout (floats): [0..NB) per-block max, [1024..1024+NB) per-block sum
#define WS_M 0
#define WS_S 1024

// ---- K_A: wave0 GRU (in-wave, barrier-free) || waves1-3 W_out stream ----
__global__ void __launch_bounds__(256, 4) fused_kernel(
        const float* __restrict__ input,
        const float* __restrict__ hidden,
        const float* __restrict__ W_ih,
        const float* __restrict__ W_hh,
        const float* __restrict__ b_ih,
        const float* __restrict__ b_hh,
        const float* __restrict__ W_out,
        const float* __restrict__ b_out,
        float* __restrict__ out,
        float* __restrict__ ws) {
    __shared__ __align__(16) float hnew[H];
    __shared__ float slog[ROWS_PER_BLOCK];
    __shared__ float pm[16], ps[16];
    const int t = threadIdx.x;
    const int sub = t & 15;
    const int grp = t >> 4;
    const int base = blockIdx.x * ROWS_PER_BLOCK;
    const float4* __restrict__ W4 = (const float4*)W_out;

    float4 w[ITERS];
    float bo[ITERS];

    if (t >= 64) {
        // waves 1-3: issue the HBM stream immediately (rows for grp 4..15)
#pragma unroll
        for (int it = 0; it < ITERS; ++it) {
            const int row = base + it * 16 + grp;
            w[it]  = W4[row * 16 + sub];  // block-contiguous, coalesced
            bo[it] = b_out[row];
        }
        __builtin_amdgcn_sched_barrier(0);  // keep loads above the barrier
    } else {
        // ---- wave 0: full GRU, within-wave only (no barriers!) ----
        const int j = t;  // lane 0..63
        float s0 = 0.f;   // softmax over singleton axis => attn weights all 1.0
#pragma unroll
        for (int i = 0; i < SEQ; ++i) s0 += input[i * H + j];
        const float h0 = hidden[j];

        // gate rows j (r), 64+j (z), 128+j (n) are lane-local
        float a0 = b_ih[j], a1 = b_ih[H + j], a2 = b_ih[2 * H + j];
        float c0 = b_hh[j], c1 = b_hh[H + j], c2 = b_hh[2 * H + j];
        const float4* Wi4 = (const float4*)W_ih;
        const float4* Wh4 = (const float4*)W_hh;
#pragma unroll
        for (int k = 0; k < H / 4; ++k) {
            // broadcast xs[4k..4k+3], h0[4k..4k+3] via shfl (no LDS hazard)
            const float x0 = __shfl(s0, 4 * k + 0), x1 = __shfl(s0, 4 * k + 1);
            const float x2 = __shfl(s0, 4 * k + 2), x3 = __shfl(s0, 4 * k + 3);
            const float g0 = __shfl(h0, 4 * k + 0), g1 = __shfl(h0, 4 * k + 1);
            const float g2 = __shfl(h0, 4 * k + 2), g3 = __shfl(h0, 4 * k + 3);
            float4 u;
            u = Wi4[j * 16 + k];            a0 += u.x * x0 + u.y * x1 + u.z * x2 + u.w * x3;
            u = Wi4[(H + j) * 16 + k];      a1 += u.x * x0 + u.y * x1 + u.z * x2 + u.w * x3;
            u = Wi4[(2 * H + j) * 16 + k];  a2 += u.x * x0 + u.y * x1 + u.z * x2 + u.w * x3;
            u = Wh4[j * 16 + k];            c0 += u.x * g0 + u.y * g1 + u.z * g2 + u.w * g3;
            u = Wh4[(H + j) * 16 + k];      c1 += u.x * g0 + u.y * g1 + u.z * g2 + u.w * g3;
            u = Wh4[(2 * H + j) * 16 + k];  c2 += u.x * g0 + u.y * g1 + u.z * g2 + u.w * g3;
        }
        const float r = 1.f / (1.f + expf(-(a0 + c0)));
        const float z = 1.f / (1.f + expf(-(a1 + c1)));
        const float n = tanhf(a2 + r * c2);
        const float hn = (1.f - z) * n + z * h0;
        hnew[j] = hn;
        if (blockIdx.x == 0) out[VOCAB + j] = hn;  // second tuple output
    }
    __syncthreads();  // single matched barrier: publishes hnew, waves1-3 drain own chunk

    const float4 hv = ((const float4*)hnew)[sub];
    if (t < 64) {
        // wave 0 loads its rows late (grp 0..3): 25% of stream, overlapped
#pragma unroll
        for (int it = 0; it < ITERS; ++it) {
            const int row = base + it * 16 + grp;
            w[it]  = W4[row * 16 + sub];
            bo[it] = b_out[row];
        }
    }

    // ---- dots + per-block LSE partial ----
    float logit[ITERS];
#pragma unroll
    for (int it = 0; it < ITERS; ++it) {
        float d = w[it].x * hv.x + w[it].y * hv.y + w[it].z * hv.z + w[it].w * hv.w;
#pragma unroll
        for (int off = 1; off < 16; off <<= 1) d += __shfl_xor(d, off);
        logit[it] = d + bo[it];
        if (sub == 0) slog[it * 16 + grp] = logit[it];
    }
    if (sub == 0) {
        float m = logit[0];
#pragma unroll
        for (int it = 1; it < ITERS; ++it) m = fmaxf(m, logit[it]);
        float s = 0.f;
#pragma unroll
        for (int it = 0; it < ITERS; ++it) s += expf(logit[it] - m);
        pm[grp] = m;
        ps[grp] = s;
    }
    __syncthreads();
    // coalesced logit store: 128 contiguous floats
    if (t < ROWS_PER_BLOCK) out[base + t] = slog[t];
    if (t == 0) {
        float M = pm[0], S = 0.f;
#pragma unroll
        for (int i = 1; i < 16; ++i) M = fmaxf(M, pm[i]);
#pragma unroll
        for (int i = 0; i < 16; ++i) S += ps[i] * expf(pm[i] - M);
        ws[WS_M + blockIdx.x] = M;
        ws[WS_S + blockIdx.x] = S;
    }
}

// ---- K_B: redundant LSE merge (8 KB from L2 per block) + in-place subtract ----
__global__ void __launch_bounds__(256) finish_kernel(float* __restrict__ out,
                                                     const float* __restrict__ ws) {
    __shared__ float pm[256], ps[256];
    const int t = threadIdx.x;
    float m = -INFINITY, s = 0.f;
    for (int i = t; i < NB; i += 256) {
        const float m2 = ws[WS_M + i], s2 = ws[WS_S + i];
        const float Mn = fmaxf(m, m2);
        s = s * expf(m - Mn) + s2 * expf(m2 - Mn);
        m = Mn;
    }
    pm[t] = m; ps[t] = s;
    __syncthreads();
    for (int off = 128; off > 0; off >>= 1) {
        if (t < off) {
            const float m2 = pm[t + off], s2 = ps[t + off];
            const float Mn = fmaxf(pm[t], m2);
            ps[t] = ps[t] * expf(pm[t] - Mn) + s2 * expf(m2 - Mn);
            pm[t] = Mn;
        }
        __syncthreads();
    }
    const float lse = pm[0] + logf(ps[0]);

    // exactly one float4 per thread: 125 blocks * 256 threads = 32000 float4
    const int i = blockIdx.x * 256 + t;
    float4* o4 = (float4*)out;
    float4 v = o4[i];
    v.x -= lse; v.y -= lse; v.z -= lse; v.w -= lse;
    o4[i] = v;
}

extern "C" void kernel_launch(void* const* d_in, const int* in_sizes, int n_in,
                              void* d_out, int out_size, void* d_ws, size_t ws_size,
                              hipStream_t stream) {
    const float* input  = (const float*)d_in[0];
    const float* hidden = (const float*)d_in[1];
    // d_in[2] = W_attn, d_in[3] = b_attn: dead (softmax over singleton axis)
    const float* W_ih   = (const float*)d_in[4];
    const float* W_hh   = (const float*)d_in[5];
    const float* b_ih   = (const float*)d_in[6];
    const float* b_hh   = (const float*)d_in[7];
    const float* W_out  = (const float*)d_in[8];
    const float* b_out  = (const float*)d_in[9];
    // d_in[10] = time_step: unused
    float* out = (float*)d_out;
    float* ws  = (float*)d_ws;

    fused_kernel<<<NB, 256, 0, stream>>>(input, hidden, W_ih, W_hh, b_ih, b_hh,
                                         W_out, b_out, out, ws);
    finish_kernel<<<VOCAB / 4 / 256, 256, 0, stream>>>(out, ws);
}